// Round 7
// baseline (609.952 us; speedup 1.0000x reference)
//
#include <hip/hip_runtime.h>
#include <math.h>

#define NPTS 80000
#define NBH 32
#define KP 15
#define CIN 128
#define COUT 256
#define D2 64
#define INFL 0.4f
#define EPS 1e-5f
#define SLOPE 0.2f

typedef __attribute__((ext_vector_type(8))) short short8;
typedef __attribute__((ext_vector_type(4))) float f32x4;

__device__ inline ushort f2b(float x) {
  unsigned u = __float_as_uint(x);
  return (ushort)((u + 0x7FFFu + ((u >> 16) & 1u)) >> 16);  // RNE
}
__device__ inline float b2f(ushort v) { return __uint_as_float(((unsigned)v) << 16); }

// ---------------- prep: feats f32->bf16, weights f32->bf16 swizzled to MFMA B-operand order
// B fragment order: Bsw[chunk][ctile][nn][q][j] <- B[k][n], k=chunk*32+q*8+j, n=ctile*16+nn
__global__ __launch_bounds__(256) void k_prep(const float* __restrict__ feats,
                                              const float* __restrict__ W1,
                                              const float* __restrict__ W2,
                                              const float* __restrict__ Wsc,
                                              const float* __restrict__ kw,
                                              ushort* __restrict__ featsb,
                                              ushort* __restrict__ w1s,
                                              ushort* __restrict__ w2s,
                                              ushort* __restrict__ wscs,
                                              ushort* __restrict__ kws) {
  const int NF4 = NPTS * CIN / 4;
  const int TOT = NF4 + 118784;
  int stride = gridDim.x * 256;
  for (int i = blockIdx.x * 256 + threadIdx.x; i < TOT; i += stride) {
    if (i < NF4) {
      float4 v = reinterpret_cast<const float4*>(feats)[i];
      ushort4 o;
      o.x = f2b(v.x); o.y = f2b(v.y); o.z = f2b(v.z); o.w = f2b(v.w);
      reinterpret_cast<ushort4*>(featsb)[i] = o;
    } else {
      int j = i - NF4;
      const float* src;
      ushort* dst;
      int logN;
      if (j < 8192)       { src = W1;  dst = w1s;  logN = 6; }
      else if (j < 24576) { j -= 8192;  src = W2;  dst = w2s;  logN = 8; }
      else if (j < 57344) { j -= 24576; src = Wsc; dst = wscs; logN = 8; }
      else                { j -= 57344; src = kw;  dst = kws;  logN = 6; }
      int N = 1 << logN, NT = N >> 4;
      int k = j >> logN, n = j & (N - 1);
      int dsti = ((k >> 5) * NT + (n >> 4)) * 512 + (n & 15) * 32 + ((k >> 3) & 3) * 8 + (k & 7);
      dst[dsti] = f2b(src[j]);
    }
  }
}

// ---------------- register-resident MFMA GEMM + fused column sum/sumsq (atomics)
// C[M x NCOLS] = A[M x 128] * B[128 x NCOLS], bf16 out. Stats computed from the same
// rounded bf16 values being stored; q-reduce via shfl_xor; one atomicAdd per col per wave.
template <int NCOLS>
__global__ __launch_bounds__(256) void k_gemm_stats(const ushort* __restrict__ A,
                                                    const ushort* __restrict__ Bsw,
                                                    ushort* __restrict__ Cb,
                                                    float* __restrict__ S,
                                                    float* __restrict__ SS) {
  constexpr int NT = NCOLS / 16;
  int tid = threadIdx.x;
  int wave = tid >> 6, lane = tid & 63;
  int nn = lane & 15, q = lane >> 4;
  int row0 = blockIdx.x * 64 + wave * 16;
  f32x4 acc[NT];
#pragma unroll
  for (int c = 0; c < NT; ++c) acc[c] = (f32x4){0.f, 0.f, 0.f, 0.f};
  const ushort* ap = A + (size_t)(row0 + nn) * CIN + q * 8;
#pragma unroll
  for (int ch = 0; ch < 4; ++ch) {
    short8 af = *reinterpret_cast<const short8*>(ap + ch * 32);
    const ushort* bp = Bsw + (size_t)ch * NT * 512 + nn * 32 + q * 8;
#pragma unroll
    for (int c = 0; c < NT; ++c) {
      short8 bf = *reinterpret_cast<const short8*>(bp + c * 512);
      acc[c] = __builtin_amdgcn_mfma_f32_16x16x32_bf16(af, bf, acc[c], 0, 0, 0);
    }
  }
#pragma unroll
  for (int c = 0; c < NT; ++c) {
    float s = 0.f, s2 = 0.f;
#pragma unroll
    for (int r = 0; r < 4; ++r) {
      ushort o = f2b(acc[c][r]);
      Cb[(size_t)(row0 + q * 4 + r) * NCOLS + c * 16 + nn] = o;
      float v = b2f(o);
      s += v; s2 += v * v;
    }
    s += __shfl_xor(s, 16); s += __shfl_xor(s, 32);
    s2 += __shfl_xor(s2, 16); s2 += __shfl_xor(s2, 32);
    if (q == 0) {
      atomicAdd(&S[c * 16 + nn], s);
      atomicAdd(&SS[c * 16 + nn], s2);
    }
  }
}

// ---------------- bn + leaky on bf16 [N,64] -> bf16
__global__ __launch_bounds__(256) void k_normb(const ushort* __restrict__ X,
                                               const float* __restrict__ sum,
                                               const float* __restrict__ sumsq,
                                               const float* __restrict__ g,
                                               const float* __restrict__ b,
                                               ushort* __restrict__ out) {
  __shared__ float sc[64], sh[64];
  int tid = threadIdx.x;
  if (tid < 64) {
    float m = sum[tid] * (1.0f / NPTS);
    float v = sumsq[tid] * (1.0f / NPTS) - m * m;
    float s = g[tid] * rsqrtf(v + EPS);
    sc[tid] = s;
    sh[tid] = b[tid] - m * s;
  }
  __syncthreads();
  const int units = NPTS * 8;  // short8 units
  int stride = gridDim.x * 256;
  for (int i = blockIdx.x * 256 + tid; i < units; i += stride) {
    short8 v = reinterpret_cast<const short8*>(X)[i];
    int cb = (i & 7) * 8;
    short8 o;
#pragma unroll
    for (int k = 0; k < 8; ++k) {
      float a = b2f((ushort)v[k]) * sc[cb + k] + sh[cb + k];
      a = a > 0.f ? a : SLOPE * a;
      o[k] = (short)f2b(a);
    }
    reinterpret_cast<short8*>(out)[i] = o;
  }
}

// ---------------- fused KPConv: gather -> stage1 MFMA -> stage2 MFMA -> unary2 MFMA
// block = 256 threads (4 waves), 16 points. Core is the verified round-4 code verbatim;
// Y3 column sum/sumsq partials fused into the epilogue (S3/SS3 atomics) — verified round 6.
__global__ __launch_bounds__(256, 3) void k_kpfused(const ushort* __restrict__ X1b,
                                                    const float* __restrict__ xyz,
                                                    const int* __restrict__ nidx,
                                                    const float* __restrict__ kpp,
                                                    const ushort* __restrict__ kws,
                                                    const ushort* __restrict__ w2s,
                                                    ushort* __restrict__ Y3b,
                                                    float* __restrict__ S3,
                                                    float* __restrict__ SS3) {
  __shared__ ushort s_xT[4][64][32];  // [wave][d][h ^ swz] gathered neighbor feats (transposed)
  __shared__ ushort s_fk[30 * 512];   // fk in stage-2 A-operand layout, 16 pts x 960
  __shared__ ushort s_y2[2 * 512];    // Y2 in u2 A-operand layout, 16 pts x 64
  int tid = threadIdx.x;
  int w = tid >> 6, lane = tid & 63;
  int q = lane >> 4, nn = lane & 15;
  int l8 = lane >> 3, c8 = lane & 7;
  int n_base = blockIdx.x * 16;

  int kidx = nn < 15 ? nn : 0;
  float kpx = kpp[kidx * 3 + 0], kpy = kpp[kidx * 3 + 1], kpz = kpp[kidx * 3 + 2];

  // ---- hoisted global loads: neighbor ids + relative coords for all 4 points
  int nb[4];
  float rx[4], ry[4], rz[4];
#pragma unroll
  for (int p = 0; p < 4; ++p) {
    int n = n_base + w * 4 + p;
    nb[p] = 0; rx[p] = 0.f; ry[p] = 0.f; rz[p] = 0.f;
    if (lane < 32) {
      int t = nidx[n * NBH + lane];
      nb[p] = t;
      rx[p] = xyz[t * 3 + 0] - xyz[n * 3 + 0];
      ry[p] = xyz[t * 3 + 1] - xyz[n * 3 + 1];
      rz[p] = xyz[t * 3 + 2] - xyz[n * 3 + 2];
    }
  }
  // ---- issue all 16 gather loads (4 points x 4 iters, 16B/lane) into registers
  short8 g[4][4];
#pragma unroll
  for (int p = 0; p < 4; ++p)
#pragma unroll
    for (int it = 0; it < 4; ++it) {
      int nbh = __shfl(nb[p], it * 8 + l8);
      g[p][it] = *reinterpret_cast<const short8*>(X1b + (size_t)nbh * 64 + c8 * 8);
    }

#pragma unroll
  for (int p = 0; p < 4; ++p) {
    // A-frag: af[j] = w[h=q*8+j][kpt=nn] (bf16)
    short8 af;
#pragma unroll
    for (int j = 0; j < 8; ++j) {
      int hh = q * 8 + j;
      float dx = __shfl(rx[p], hh) - kpx;
      float dy = __shfl(ry[p], hh) - kpy;
      float dz = __shfl(rz[p], hh) - kpz;
      float dist = sqrtf(dx * dx + dy * dy + dz * dz);
      float wv = fmaxf(1.0f - dist * (1.0f / INFL), 0.0f);
      if (nn == 15) wv = 0.f;
      af[j] = (short)f2b(wv);
    }
    // transpose gathered rows into s_xT with XOR swizzle (baseline-verified layout)
#pragma unroll
    for (int it = 0; it < 4; ++it) {
      int hh = it * 8 + l8;
      int hcol = hh ^ ((c8 & 3) << 3);  // key = (d>>3)&3 = c8&3
#pragma unroll
      for (int u = 0; u < 8; ++u) s_xT[w][c8 * 8 + u][hcol] = (ushort)g[p][it][u];
    }
    // stage-1 MFMA: fk[kpt][d] = sum_h w[h][kpt] * x[h][d]
    f32x4 acc[4];
#pragma unroll
    for (int c = 0; c < 4; ++c) {
      int d = c * 16 + nn;
      int key = (d >> 3) & 3;
      short8 bf = *reinterpret_cast<const short8*>(&s_xT[w][d][(q ^ key) << 3]);
      acc[c] = __builtin_amdgcn_mfma_f32_16x16x32_bf16(af, bf, (f32x4){0.f, 0.f, 0.f, 0.f}, 0, 0, 0);
    }
    // write fk -> s_fk in stage-2 A layout (kappa = kpt*64 + d), XOR-swizzled (conflict-free)
    int m = w * 4 + p;
#pragma unroll
    for (int c = 0; c < 4; ++c) {
#pragma unroll
      for (int r = 0; r < 4; ++r) {
        int kpt = q * 4 + r;
        if (kpt < 15) {
          int kap = kpt * 64 + c * 16 + nn;
          int ch = kap >> 5, t = kap & 31;
          int tp = t ^ (((ch >> 3) & 3) << 3);
          s_fk[ch * 512 + m * 32 + tp] = f2b(acc[c][r]);
        }
      }
    }
  }
  __syncthreads();

  // stage-2: Y2[16 x 64] = FK[16 x 960] * kw[960 x 64]; wave w owns col tile w
  f32x4 acc2 = (f32x4){0.f, 0.f, 0.f, 0.f};
  for (int ch = 0; ch < 30; ++ch) {
    int key = (ch >> 3) & 3;
    short8 a = *reinterpret_cast<const short8*>(&s_fk[ch * 512 + nn * 32 + ((q ^ key) << 3)]);
    short8 b = *reinterpret_cast<const short8*>(kws + (size_t)ch * 2048 + w * 512 + nn * 32 + q * 8);
    acc2 = __builtin_amdgcn_mfma_f32_16x16x32_bf16(a, b, acc2, 0, 0, 0);
  }
  {
    int e = w * 16 + nn;
    int ch2 = e >> 5, t = e & 31;
#pragma unroll
    for (int r = 0; r < 4; ++r) {
      int mm = q * 4 + r;
      int tp = t ^ (((mm >> 2) & 3) << 3);
      s_y2[ch2 * 512 + mm * 32 + tp] = f2b(acc2[r]);
    }
  }
  __syncthreads();

  // unary_2: Y3[16 x 256] = Y2[16 x 64] * W2[64 x 256]; wave w owns col tiles w*4..w*4+3
  short8 a0, a1;
  {
    int key = (nn >> 2) & 3;
    a0 = *reinterpret_cast<const short8*>(&s_y2[0 * 512 + nn * 32 + ((q ^ key) << 3)]);
    a1 = *reinterpret_cast<const short8*>(&s_y2[1 * 512 + nn * 32 + ((q ^ key) << 3)]);
  }
#pragma unroll
  for (int t4 = 0; t4 < 4; ++t4) {
    int ct = w * 4 + t4;
    short8 b0 = *reinterpret_cast<const short8*>(w2s + (0 * 16 + ct) * 512 + nn * 32 + q * 8);
    short8 b1 = *reinterpret_cast<const short8*>(w2s + (1 * 16 + ct) * 512 + nn * 32 + q * 8);
    f32x4 a = __builtin_amdgcn_mfma_f32_16x16x32_bf16(a0, b0, (f32x4){0.f, 0.f, 0.f, 0.f}, 0, 0, 0);
    a = __builtin_amdgcn_mfma_f32_16x16x32_bf16(a1, b1, a, 0, 0, 0);
    float s = 0.f, s2 = 0.f;
#pragma unroll
    for (int r = 0; r < 4; ++r) {
      ushort o = f2b(a[r]);
      Y3b[(size_t)(n_base + q * 4 + r) * 256 + ct * 16 + nn] = o;
      float v = b2f(o);
      s += v; s2 += v * v;
    }
    s += __shfl_xor(s, 16); s += __shfl_xor(s, 32);
    s2 += __shfl_xor(s2, 16); s2 += __shfl_xor(s2, 32);
    if (q == 0) {
      atomicAdd(&S3[ct * 16 + nn], s);
      atomicAdd(&SS3[ct * 16 + nn], s2);
    }
  }
}

// ---------------- final: out = leaky(bn(Y3b)) + bn(YSCb), f32 out
__global__ __launch_bounds__(256) void k_final(const ushort* __restrict__ Y3,
                                               const ushort* __restrict__ YSC,
                                               const float* __restrict__ s3,
                                               const float* __restrict__ ss3,
                                               const float* __restrict__ g2,
                                               const float* __restrict__ b2,
                                               const float* __restrict__ ssc,
                                               const float* __restrict__ sssc,
                                               const float* __restrict__ gsc,
                                               const float* __restrict__ bsc,
                                               float* __restrict__ out) {
  __shared__ float sc3[256], sh3[256], scc[256], shc[256];
  int tid = threadIdx.x;
  {
    float m = s3[tid] * (1.0f / NPTS);
    float v = ss3[tid] * (1.0f / NPTS) - m * m;
    float s = g2[tid] * rsqrtf(v + EPS);
    sc3[tid] = s;
    sh3[tid] = b2[tid] - m * s;
    m = ssc[tid] * (1.0f / NPTS);
    v = sssc[tid] * (1.0f / NPTS) - m * m;
    s = gsc[tid] * rsqrtf(v + EPS);
    scc[tid] = s;
    shc[tid] = bsc[tid] - m * s;
  }
  __syncthreads();
  const int units = NPTS * 32;  // short8 units per matrix
  int stride = gridDim.x * 256;
  for (int i = blockIdx.x * 256 + tid; i < units; i += stride) {
    short8 a = reinterpret_cast<const short8*>(Y3)[i];
    short8 b = reinterpret_cast<const short8*>(YSC)[i];
    int cb = (i & 31) * 8;
    float o[8];
#pragma unroll
    for (int k = 0; k < 8; ++k) {
      float x = b2f((ushort)a[k]) * sc3[cb + k] + sh3[cb + k];
      x = x > 0.f ? x : SLOPE * x;
      o[k] = x + b2f((ushort)b[k]) * scc[cb + k] + shc[cb + k];
    }
    float4* O4 = reinterpret_cast<float4*>(out + (size_t)i * 8);
    O4[0] = make_float4(o[0], o[1], o[2], o[3]);
    O4[1] = make_float4(o[4], o[5], o[6], o[7]);
  }
}

extern "C" void kernel_launch(void* const* d_in, const int* in_sizes, int n_in,
                              void* d_out, int out_size, void* d_ws, size_t ws_size,
                              hipStream_t stream) {
  const float* feats = (const float*)d_in[0];
  const float* xyz   = (const float*)d_in[1];
  const int* nidx    = (const int*)d_in[3];
  const float* W1    = (const float*)d_in[4];
  const float* g1    = (const float*)d_in[5];
  const float* b1    = (const float*)d_in[6];
  const float* kpp   = (const float*)d_in[7];
  const float* kw    = (const float*)d_in[8];
  const float* W2    = (const float*)d_in[9];
  const float* g2    = (const float*)d_in[10];
  const float* b2    = (const float*)d_in[11];
  const float* Wsc   = (const float*)d_in[12];
  const float* gsc   = (const float*)d_in[13];
  const float* bsc   = (const float*)d_in[14];
  float* out = (float*)d_out;

  // workspace (bytes): featsb 20.48M | X1r 10.24M | X1b 10.24M | Y3b 40.96M | YSCb 40.96M | weights | stats
  char* ws = (char*)d_ws;
  ushort* featsb = (ushort*)ws;
  ushort* X1r    = (ushort*)(ws + 20480000);
  ushort* X1b    = (ushort*)(ws + 30720000);
  ushort* Y3b    = (ushort*)(ws + 40960000);
  ushort* YSCb   = (ushort*)(ws + 81920000);
  ushort* w1s    = (ushort*)(ws + 122880000);
  ushort* w2s    = w1s + 8192;
  ushort* wscs   = w2s + 16384;
  ushort* kws    = wscs + 32768;
  float*  ST     = (float*)(kws + 61440);
  float *S1 = ST, *SS1 = ST + 64;
  float *S3 = ST + 128, *SS3 = ST + 384;
  float *SSC = ST + 640, *SSSC = ST + 896;

  hipMemsetAsync(ST, 0, 1152 * sizeof(float), stream);
  k_prep<<<2048, 256, 0, stream>>>(feats, W1, W2, Wsc, kw, featsb, w1s, w2s, wscs, kws);
  // unary_1 GEMM (+ fused col stats)
  k_gemm_stats<64><<<1250, 256, 0, stream>>>(featsb, w1s, X1r, S1, SS1);
  k_normb<<<512, 256, 0, stream>>>(X1r, S1, SS1, g1, b1, X1b);
  // shortcut GEMM (+ fused col stats), independent
  k_gemm_stats<256><<<1250, 256, 0, stream>>>(featsb, wscs, YSCb, SSC, SSSC);
  // fused KPConv + unary_2 (+ Y3 col stats)
  k_kpfused<<<NPTS / 16, 256, 0, stream>>>(X1b, xyz, nidx, kpp, kws, w2s, Y3b, S3, SS3);
  // out = leaky(bn(Y3b)) + bn(YSCb)
  k_final<<<1024, 256, 0, stream>>>(Y3b, YSCb, S3, SS3, g2, b2, SSC, SSSC, gsc, bsc, out);
}

// Round 8
// 369.314 us; speedup vs baseline: 1.6516x; 1.6516x over previous
//
#include <hip/hip_runtime.h>
#include <math.h>

#define NPTS 80000
#define NBH 32
#define KP 15
#define CIN 128
#define COUT 256
#define D2 64
#define INFL 0.4f
#define EPS 1e-5f
#define SLOPE 0.2f

typedef __attribute__((ext_vector_type(8))) short short8;
typedef __attribute__((ext_vector_type(4))) float f32x4;

__device__ inline ushort f2b(float x) {
  unsigned u = __float_as_uint(x);
  return (ushort)((u + 0x7FFFu + ((u >> 16) & 1u)) >> 16);  // RNE
}
__device__ inline float b2f(ushort v) { return __uint_as_float(((unsigned)v) << 16); }

// ---------------- prep: feats f32->bf16, weights f32->bf16 swizzled to MFMA B-operand order
// B fragment order: Bsw[chunk][ctile][nn][q][j] <- B[k][n], k=chunk*32+q*8+j, n=ctile*16+nn
__global__ __launch_bounds__(256) void k_prep(const float* __restrict__ feats,
                                              const float* __restrict__ W1,
                                              const float* __restrict__ W2,
                                              const float* __restrict__ Wsc,
                                              const float* __restrict__ kw,
                                              ushort* __restrict__ featsb,
                                              ushort* __restrict__ w1s,
                                              ushort* __restrict__ w2s,
                                              ushort* __restrict__ wscs,
                                              ushort* __restrict__ kws) {
  const int NF4 = NPTS * CIN / 4;
  const int TOT = NF4 + 118784;
  int stride = gridDim.x * 256;
  for (int i = blockIdx.x * 256 + threadIdx.x; i < TOT; i += stride) {
    if (i < NF4) {
      float4 v = reinterpret_cast<const float4*>(feats)[i];
      ushort4 o;
      o.x = f2b(v.x); o.y = f2b(v.y); o.z = f2b(v.z); o.w = f2b(v.w);
      reinterpret_cast<ushort4*>(featsb)[i] = o;
    } else {
      int j = i - NF4;
      const float* src;
      ushort* dst;
      int logN;
      if (j < 8192)       { src = W1;  dst = w1s;  logN = 6; }
      else if (j < 24576) { j -= 8192;  src = W2;  dst = w2s;  logN = 8; }
      else if (j < 57344) { j -= 24576; src = Wsc; dst = wscs; logN = 8; }
      else                { j -= 57344; src = kw;  dst = kws;  logN = 6; }
      int N = 1 << logN, NT = N >> 4;
      int k = j >> logN, n = j & (N - 1);
      int dsti = ((k >> 5) * NT + (n >> 4)) * 512 + (n & 15) * 32 + ((k >> 3) & 3) * 8 + (k & 7);
      dst[dsti] = f2b(src[j]);
    }
  }
}

// ---------------- register-resident MFMA GEMM, bf16 out: C[M x NCOLS] = A[M x K] * B[K x NCOLS]
template <int NCOLS>
__global__ __launch_bounds__(256) void k_gemm_mfma(const ushort* __restrict__ A,
                                                   const ushort* __restrict__ Bsw,
                                                   ushort* __restrict__ Cb, int K) {
  constexpr int NT = NCOLS / 16;
  int tid = threadIdx.x;
  int wave = tid >> 6, lane = tid & 63;
  int nn = lane & 15, q = lane >> 4;
  int row0 = blockIdx.x * 64 + wave * 16;
  f32x4 acc[NT];
#pragma unroll
  for (int c = 0; c < NT; ++c) acc[c] = (f32x4){0.f, 0.f, 0.f, 0.f};
  const ushort* ap = A + (size_t)(row0 + nn) * K + q * 8;
  int nch = K >> 5;
  for (int ch = 0; ch < nch; ++ch) {
    short8 af = *reinterpret_cast<const short8*>(ap + (size_t)ch * 32);
    const ushort* bp = Bsw + (size_t)ch * NT * 512 + nn * 32 + q * 8;
#pragma unroll
    for (int c = 0; c < NT; ++c) {
      short8 bf = *reinterpret_cast<const short8*>(bp + c * 512);
      acc[c] = __builtin_amdgcn_mfma_f32_16x16x32_bf16(af, bf, acc[c], 0, 0, 0);
    }
  }
#pragma unroll
  for (int c = 0; c < NT; ++c)
#pragma unroll
    for (int r = 0; r < 4; ++r)
      Cb[(size_t)(row0 + q * 4 + r) * NCOLS + c * 16 + nn] = f2b(acc[c][r]);
}

// ---------------- per-column sum/sumsq over bf16 matrix (vectorized, LDS reduce)
__global__ __launch_bounds__(256) void k_colstats_b16(const ushort* __restrict__ X, int units,
                                                      int cols, float* __restrict__ sum,
                                                      float* __restrict__ sumsq) {
  __shared__ float ls[2048], ls2[2048];
  int tid = threadIdx.x;
  int stride = gridDim.x * 256;  // divisible by cols/8
  float s[8], s2[8];
#pragma unroll
  for (int k = 0; k < 8; ++k) { s[k] = 0.f; s2[k] = 0.f; }
  for (int i = blockIdx.x * 256 + tid; i < units; i += stride) {
    short8 v = reinterpret_cast<const short8*>(X)[i];
#pragma unroll
    for (int k = 0; k < 8; ++k) {
      float f = b2f((ushort)v[k]);
      s[k] += f;
      s2[k] += f * f;
    }
  }
#pragma unroll
  for (int k = 0; k < 8; ++k) { ls[tid * 8 + k] = s[k]; ls2[tid * 8 + k] = s2[k]; }
  __syncthreads();
  if (tid < cols) {
    int P = cols >> 3;
    float a = 0.f, a2 = 0.f;
    for (int t = (tid >> 3); t < 256; t += P) {
      a += ls[t * 8 + (tid & 7)];
      a2 += ls2[t * 8 + (tid & 7)];
    }
    atomicAdd(&sum[tid], a);
    atomicAdd(&sumsq[tid], a2);
  }
}

// ---------------- dual per-column sum/sumsq over TWO [NPTS x 256] bf16 matrices, one pass
__global__ __launch_bounds__(256) void k_colstats_dual(const ushort* __restrict__ XA,
                                                       const ushort* __restrict__ XB,
                                                       float* __restrict__ sumA,
                                                       float* __restrict__ sumsqA,
                                                       float* __restrict__ sumB,
                                                       float* __restrict__ sumsqB) {
  __shared__ float ls[2048], ls2[2048];
  const int units = NPTS * 32;  // short8 units per matrix (256 cols)
  int tid = threadIdx.x;
  int stride = gridDim.x * 256;  // 256*256 = 65536, divisible by 32
  float sa[8], s2a[8], sb[8], s2b[8];
#pragma unroll
  for (int k = 0; k < 8; ++k) { sa[k] = 0.f; s2a[k] = 0.f; sb[k] = 0.f; s2b[k] = 0.f; }
  for (int i = blockIdx.x * 256 + tid; i < units; i += stride) {
    short8 va = reinterpret_cast<const short8*>(XA)[i];
    short8 vb = reinterpret_cast<const short8*>(XB)[i];
#pragma unroll
    for (int k = 0; k < 8; ++k) {
      float fa = b2f((ushort)va[k]);
      sa[k] += fa; s2a[k] += fa * fa;
      float fb = b2f((ushort)vb[k]);
      sb[k] += fb; s2b[k] += fb * fb;
    }
  }
  // reduce set A
#pragma unroll
  for (int k = 0; k < 8; ++k) { ls[tid * 8 + k] = sa[k]; ls2[tid * 8 + k] = s2a[k]; }
  __syncthreads();
  {
    float a = 0.f, a2 = 0.f;
    for (int t = (tid >> 3); t < 256; t += 32) {
      a += ls[t * 8 + (tid & 7)];
      a2 += ls2[t * 8 + (tid & 7)];
    }
    atomicAdd(&sumA[tid], a);
    atomicAdd(&sumsqA[tid], a2);
  }
  __syncthreads();
  // reduce set B
#pragma unroll
  for (int k = 0; k < 8; ++k) { ls[tid * 8 + k] = sb[k]; ls2[tid * 8 + k] = s2b[k]; }
  __syncthreads();
  {
    float a = 0.f, a2 = 0.f;
    for (int t = (tid >> 3); t < 256; t += 32) {
      a += ls[t * 8 + (tid & 7)];
      a2 += ls2[t * 8 + (tid & 7)];
    }
    atomicAdd(&sumB[tid], a);
    atomicAdd(&sumsqB[tid], a2);
  }
}

// ---------------- bn + leaky on bf16 [N,64] -> bf16
__global__ __launch_bounds__(256) void k_normb(const ushort* __restrict__ X,
                                               const float* __restrict__ sum,
                                               const float* __restrict__ sumsq,
                                               const float* __restrict__ g,
                                               const float* __restrict__ b,
                                               ushort* __restrict__ out) {
  __shared__ float sc[64], sh[64];
  int tid = threadIdx.x;
  if (tid < 64) {
    float m = sum[tid] * (1.0f / NPTS);
    float v = sumsq[tid] * (1.0f / NPTS) - m * m;
    float s = g[tid] * rsqrtf(v + EPS);
    sc[tid] = s;
    sh[tid] = b[tid] - m * s;
  }
  __syncthreads();
  const int units = NPTS * 8;  // short8 units
  int stride = gridDim.x * 256;
  for (int i = blockIdx.x * 256 + tid; i < units; i += stride) {
    short8 v = reinterpret_cast<const short8*>(X)[i];
    int cb = (i & 7) * 8;
    short8 o;
#pragma unroll
    for (int k = 0; k < 8; ++k) {
      float a = b2f((ushort)v[k]) * sc[cb + k] + sh[cb + k];
      a = a > 0.f ? a : SLOPE * a;
      o[k] = (short)f2b(a);
    }
    reinterpret_cast<short8*>(out)[i] = o;
  }
}

// ---------------- fused KPConv: gather -> stage1 MFMA -> stage2 MFMA -> unary2 MFMA
// block = 256 threads (4 waves), 16 points. Verified round-4 code verbatim.
__global__ __launch_bounds__(256, 3) void k_kpfused(const ushort* __restrict__ X1b,
                                                    const float* __restrict__ xyz,
                                                    const int* __restrict__ nidx,
                                                    const float* __restrict__ kpp,
                                                    const ushort* __restrict__ kws,
                                                    const ushort* __restrict__ w2s,
                                                    ushort* __restrict__ Y3b) {
  __shared__ ushort s_xT[4][64][32];  // [wave][d][h ^ swz] gathered neighbor feats (transposed)
  __shared__ ushort s_fk[30 * 512];   // fk in stage-2 A-operand layout, 16 pts x 960
  __shared__ ushort s_y2[2 * 512];    // Y2 in u2 A-operand layout, 16 pts x 64
  int tid = threadIdx.x;
  int w = tid >> 6, lane = tid & 63;
  int q = lane >> 4, nn = lane & 15;
  int l8 = lane >> 3, c8 = lane & 7;
  int n_base = blockIdx.x * 16;

  int kidx = nn < 15 ? nn : 0;
  float kpx = kpp[kidx * 3 + 0], kpy = kpp[kidx * 3 + 1], kpz = kpp[kidx * 3 + 2];

  // ---- hoisted global loads: neighbor ids + relative coords for all 4 points
  int nb[4];
  float rx[4], ry[4], rz[4];
#pragma unroll
  for (int p = 0; p < 4; ++p) {
    int n = n_base + w * 4 + p;
    nb[p] = 0; rx[p] = 0.f; ry[p] = 0.f; rz[p] = 0.f;
    if (lane < 32) {
      int t = nidx[n * NBH + lane];
      nb[p] = t;
      rx[p] = xyz[t * 3 + 0] - xyz[n * 3 + 0];
      ry[p] = xyz[t * 3 + 1] - xyz[n * 3 + 1];
      rz[p] = xyz[t * 3 + 2] - xyz[n * 3 + 2];
    }
  }
  // ---- issue all 16 gather loads (4 points x 4 iters, 16B/lane) into registers
  short8 g[4][4];
#pragma unroll
  for (int p = 0; p < 4; ++p)
#pragma unroll
    for (int it = 0; it < 4; ++it) {
      int nbh = __shfl(nb[p], it * 8 + l8);
      g[p][it] = *reinterpret_cast<const short8*>(X1b + (size_t)nbh * 64 + c8 * 8);
    }

#pragma unroll
  for (int p = 0; p < 4; ++p) {
    // A-frag: af[j] = w[h=q*8+j][kpt=nn] (bf16)
    short8 af;
#pragma unroll
    for (int j = 0; j < 8; ++j) {
      int hh = q * 8 + j;
      float dx = __shfl(rx[p], hh) - kpx;
      float dy = __shfl(ry[p], hh) - kpy;
      float dz = __shfl(rz[p], hh) - kpz;
      float dist = sqrtf(dx * dx + dy * dy + dz * dz);
      float wv = fmaxf(1.0f - dist * (1.0f / INFL), 0.0f);
      if (nn == 15) wv = 0.f;
      af[j] = (short)f2b(wv);
    }
    // transpose gathered rows into s_xT with XOR swizzle (baseline-verified layout)
#pragma unroll
    for (int it = 0; it < 4; ++it) {
      int hh = it * 8 + l8;
      int hcol = hh ^ ((c8 & 3) << 3);  // key = (d>>3)&3 = c8&3
#pragma unroll
      for (int u = 0; u < 8; ++u) s_xT[w][c8 * 8 + u][hcol] = (ushort)g[p][it][u];
    }
    // stage-1 MFMA: fk[kpt][d] = sum_h w[h][kpt] * x[h][d]
    f32x4 acc[4];
#pragma unroll
    for (int c = 0; c < 4; ++c) {
      int d = c * 16 + nn;
      int key = (d >> 3) & 3;
      short8 bf = *reinterpret_cast<const short8*>(&s_xT[w][d][(q ^ key) << 3]);
      acc[c] = __builtin_amdgcn_mfma_f32_16x16x32_bf16(af, bf, (f32x4){0.f, 0.f, 0.f, 0.f}, 0, 0, 0);
    }
    // write fk -> s_fk in stage-2 A layout (kappa = kpt*64 + d), XOR-swizzled (conflict-free)
    int m = w * 4 + p;
#pragma unroll
    for (int c = 0; c < 4; ++c) {
#pragma unroll
      for (int r = 0; r < 4; ++r) {
        int kpt = q * 4 + r;
        if (kpt < 15) {
          int kap = kpt * 64 + c * 16 + nn;
          int ch = kap >> 5, t = kap & 31;
          int tp = t ^ (((ch >> 3) & 3) << 3);
          s_fk[ch * 512 + m * 32 + tp] = f2b(acc[c][r]);
        }
      }
    }
  }
  __syncthreads();

  // stage-2: Y2[16 x 64] = FK[16 x 960] * kw[960 x 64]; wave w owns col tile w
  f32x4 acc2 = (f32x4){0.f, 0.f, 0.f, 0.f};
  for (int ch = 0; ch < 30; ++ch) {
    int key = (ch >> 3) & 3;
    short8 a = *reinterpret_cast<const short8*>(&s_fk[ch * 512 + nn * 32 + ((q ^ key) << 3)]);
    short8 b = *reinterpret_cast<const short8*>(kws + (size_t)ch * 2048 + w * 512 + nn * 32 + q * 8);
    acc2 = __builtin_amdgcn_mfma_f32_16x16x32_bf16(a, b, acc2, 0, 0, 0);
  }
  {
    int e = w * 16 + nn;
    int ch2 = e >> 5, t = e & 31;
#pragma unroll
    for (int r = 0; r < 4; ++r) {
      int mm = q * 4 + r;
      int tp = t ^ (((mm >> 2) & 3) << 3);
      s_y2[ch2 * 512 + mm * 32 + tp] = f2b(acc2[r]);
    }
  }
  __syncthreads();

  // unary_2: Y3[16 x 256] = Y2[16 x 64] * W2[64 x 256]; wave w owns col tiles w*4..w*4+3
  short8 a0, a1;
  {
    int key = (nn >> 2) & 3;
    a0 = *reinterpret_cast<const short8*>(&s_y2[0 * 512 + nn * 32 + ((q ^ key) << 3)]);
    a1 = *reinterpret_cast<const short8*>(&s_y2[1 * 512 + nn * 32 + ((q ^ key) << 3)]);
  }
#pragma unroll
  for (int t4 = 0; t4 < 4; ++t4) {
    int ct = w * 4 + t4;
    short8 b0 = *reinterpret_cast<const short8*>(w2s + (0 * 16 + ct) * 512 + nn * 32 + q * 8);
    short8 b1 = *reinterpret_cast<const short8*>(w2s + (1 * 16 + ct) * 512 + nn * 32 + q * 8);
    f32x4 a = __builtin_amdgcn_mfma_f32_16x16x32_bf16(a0, b0, (f32x4){0.f, 0.f, 0.f, 0.f}, 0, 0, 0);
    a = __builtin_amdgcn_mfma_f32_16x16x32_bf16(a1, b1, a, 0, 0, 0);
#pragma unroll
    for (int r = 0; r < 4; ++r)
      Y3b[(size_t)(n_base + q * 4 + r) * 256 + ct * 16 + nn] = f2b(a[r]);
  }
}

// ---------------- final: out = leaky(bn(Y3b)) + bn(YSCb), f32 out
__global__ __launch_bounds__(256) void k_final(const ushort* __restrict__ Y3,
                                               const ushort* __restrict__ YSC,
                                               const float* __restrict__ s3,
                                               const float* __restrict__ ss3,
                                               const float* __restrict__ g2,
                                               const float* __restrict__ b2,
                                               const float* __restrict__ ssc,
                                               const float* __restrict__ sssc,
                                               const float* __restrict__ gsc,
                                               const float* __restrict__ bsc,
                                               float* __restrict__ out) {
  __shared__ float sc3[256], sh3[256], scc[256], shc[256];
  int tid = threadIdx.x;
  {
    float m = s3[tid] * (1.0f / NPTS);
    float v = ss3[tid] * (1.0f / NPTS) - m * m;
    float s = g2[tid] * rsqrtf(v + EPS);
    sc3[tid] = s;
    sh3[tid] = b2[tid] - m * s;
    m = ssc[tid] * (1.0f / NPTS);
    v = sssc[tid] * (1.0f / NPTS) - m * m;
    s = gsc[tid] * rsqrtf(v + EPS);
    scc[tid] = s;
    shc[tid] = bsc[tid] - m * s;
  }
  __syncthreads();
  const int units = NPTS * 32;  // short8 units per matrix
  int stride = gridDim.x * 256;
  for (int i = blockIdx.x * 256 + tid; i < units; i += stride) {
    short8 a = reinterpret_cast<const short8*>(Y3)[i];
    short8 b = reinterpret_cast<const short8*>(YSC)[i];
    int cb = (i & 31) * 8;
    float o[8];
#pragma unroll
    for (int k = 0; k < 8; ++k) {
      float x = b2f((ushort)a[k]) * sc3[cb + k] + sh3[cb + k];
      x = x > 0.f ? x : SLOPE * x;
      o[k] = x + b2f((ushort)b[k]) * scc[cb + k] + shc[cb + k];
    }
    float4* O4 = reinterpret_cast<float4*>(out + (size_t)i * 8);
    O4[0] = make_float4(o[0], o[1], o[2], o[3]);
    O4[1] = make_float4(o[4], o[5], o[6], o[7]);
  }
}

extern "C" void kernel_launch(void* const* d_in, const int* in_sizes, int n_in,
                              void* d_out, int out_size, void* d_ws, size_t ws_size,
                              hipStream_t stream) {
  const float* feats = (const float*)d_in[0];
  const float* xyz   = (const float*)d_in[1];
  const int* nidx    = (const int*)d_in[3];
  const float* W1    = (const float*)d_in[4];
  const float* g1    = (const float*)d_in[5];
  const float* b1    = (const float*)d_in[6];
  const float* kpp   = (const float*)d_in[7];
  const float* kw    = (const float*)d_in[8];
  const float* W2    = (const float*)d_in[9];
  const float* g2    = (const float*)d_in[10];
  const float* b2    = (const float*)d_in[11];
  const float* Wsc   = (const float*)d_in[12];
  const float* gsc   = (const float*)d_in[13];
  const float* bsc   = (const float*)d_in[14];
  float* out = (float*)d_out;

  // workspace (bytes): featsb 20.48M | X1r 10.24M | X1b 10.24M | Y3b 40.96M | YSCb 40.96M | weights | stats
  char* ws = (char*)d_ws;
  ushort* featsb = (ushort*)ws;
  ushort* X1r    = (ushort*)(ws + 20480000);
  ushort* X1b    = (ushort*)(ws + 30720000);
  ushort* Y3b    = (ushort*)(ws + 40960000);
  ushort* YSCb   = (ushort*)(ws + 81920000);
  ushort* w1s    = (ushort*)(ws + 122880000);
  ushort* w2s    = w1s + 8192;
  ushort* wscs   = w2s + 16384;
  ushort* kws    = wscs + 32768;
  float*  ST     = (float*)(kws + 61440);
  float *S1 = ST, *SS1 = ST + 64;
  float *S3 = ST + 128, *SS3 = ST + 384;
  float *SSC = ST + 640, *SSSC = ST + 896;

  hipMemsetAsync(ST, 0, 1152 * sizeof(float), stream);
  k_prep<<<2048, 256, 0, stream>>>(feats, W1, W2, Wsc, kw, featsb, w1s, w2s, wscs, kws);
  // unary_1
  k_gemm_mfma<64><<<1250, 256, 0, stream>>>(featsb, w1s, X1r, 128);
  k_colstats_b16<<<256, 256, 0, stream>>>(X1r, NPTS * 8, 64, S1, SS1);
  k_normb<<<512, 256, 0, stream>>>(X1r, S1, SS1, g1, b1, X1b);
  // shortcut (independent; stats deferred to the dual pass after kpfused)
  k_gemm_mfma<256><<<1250, 256, 0, stream>>>(featsb, wscs, YSCb, 128);
  // fused KPConv + unary_2
  k_kpfused<<<NPTS / 16, 256, 0, stream>>>(X1b, xyz, nidx, kpp, kws, w2s, Y3b);
  // one-pass column stats over Y3b and YSCb together
  k_colstats_dual<<<256, 256, 0, stream>>>(Y3b, YSCb, S3, SS3, SSC, SSSC);
  // out = leaky(bn(Y3b)) + bn(YSCb)
  k_final<<<1024, 256, 0, stream>>>(Y3b, YSCb, S3, SS3, g2, b2, SSC, SSSC, gsc, bsc, out);
}

// Round 9
// 362.126 us; speedup vs baseline: 1.6844x; 1.0198x over previous
//
#include <hip/hip_runtime.h>
#include <math.h>

#define NPTS 80000
#define NBH 32
#define KP 15
#define CIN 128
#define COUT 256
#define D2 64
#define INFL 0.4f
#define EPS 1e-5f
#define SLOPE 0.2f

typedef __attribute__((ext_vector_type(8))) short short8;
typedef __attribute__((ext_vector_type(4))) float f32x4;

__device__ inline ushort f2b(float x) {
  unsigned u = __float_as_uint(x);
  return (ushort)((u + 0x7FFFu + ((u >> 16) & 1u)) >> 16);  // RNE
}
__device__ inline float b2f(ushort v) { return __uint_as_float(((unsigned)v) << 16); }

// ---------------- prep: feats f32->bf16, weights f32->bf16 swizzled to MFMA B-operand order
// B fragment order: Bsw[chunk][ctile][nn][q][j] <- B[k][n], k=chunk*32+q*8+j, n=ctile*16+nn
__global__ __launch_bounds__(256) void k_prep(const float* __restrict__ feats,
                                              const float* __restrict__ W1,
                                              const float* __restrict__ W2,
                                              const float* __restrict__ Wsc,
                                              const float* __restrict__ kw,
                                              ushort* __restrict__ featsb,
                                              ushort* __restrict__ w1s,
                                              ushort* __restrict__ w2s,
                                              ushort* __restrict__ wscs,
                                              ushort* __restrict__ kws) {
  const int NF4 = NPTS * CIN / 4;
  const int TOT = NF4 + 118784;
  int stride = gridDim.x * 256;
  for (int i = blockIdx.x * 256 + threadIdx.x; i < TOT; i += stride) {
    if (i < NF4) {
      float4 v = reinterpret_cast<const float4*>(feats)[i];
      ushort4 o;
      o.x = f2b(v.x); o.y = f2b(v.y); o.z = f2b(v.z); o.w = f2b(v.w);
      reinterpret_cast<ushort4*>(featsb)[i] = o;
    } else {
      int j = i - NF4;
      const float* src;
      ushort* dst;
      int logN;
      if (j < 8192)       { src = W1;  dst = w1s;  logN = 6; }
      else if (j < 24576) { j -= 8192;  src = W2;  dst = w2s;  logN = 8; }
      else if (j < 57344) { j -= 24576; src = Wsc; dst = wscs; logN = 8; }
      else                { j -= 57344; src = kw;  dst = kws;  logN = 6; }
      int N = 1 << logN, NT = N >> 4;
      int k = j >> logN, n = j & (N - 1);
      int dsti = ((k >> 5) * NT + (n >> 4)) * 512 + (n & 15) * 32 + ((k >> 3) & 3) * 8 + (k & 7);
      dst[dsti] = f2b(src[j]);
    }
  }
}

// ---------------- register-resident MFMA GEMM, bf16 out: C[M x NCOLS] = A[M x K] * B[K x NCOLS]
template <int NCOLS>
__global__ __launch_bounds__(256) void k_gemm_mfma(const ushort* __restrict__ A,
                                                   const ushort* __restrict__ Bsw,
                                                   ushort* __restrict__ Cb, int K) {
  constexpr int NT = NCOLS / 16;
  int tid = threadIdx.x;
  int wave = tid >> 6, lane = tid & 63;
  int nn = lane & 15, q = lane >> 4;
  int row0 = blockIdx.x * 64 + wave * 16;
  f32x4 acc[NT];
#pragma unroll
  for (int c = 0; c < NT; ++c) acc[c] = (f32x4){0.f, 0.f, 0.f, 0.f};
  const ushort* ap = A + (size_t)(row0 + nn) * K + q * 8;
  int nch = K >> 5;
  for (int ch = 0; ch < nch; ++ch) {
    short8 af = *reinterpret_cast<const short8*>(ap + (size_t)ch * 32);
    const ushort* bp = Bsw + (size_t)ch * NT * 512 + nn * 32 + q * 8;
#pragma unroll
    for (int c = 0; c < NT; ++c) {
      short8 bf = *reinterpret_cast<const short8*>(bp + c * 512);
      acc[c] = __builtin_amdgcn_mfma_f32_16x16x32_bf16(af, bf, acc[c], 0, 0, 0);
    }
  }
#pragma unroll
  for (int c = 0; c < NT; ++c)
#pragma unroll
    for (int r = 0; r < 4; ++r)
      Cb[(size_t)(row0 + q * 4 + r) * NCOLS + c * 16 + nn] = f2b(acc[c][r]);
}

// ---------------- per-column sum/sumsq over bf16 matrix (vectorized, LDS reduce)
__global__ __launch_bounds__(256) void k_colstats_b16(const ushort* __restrict__ X, int units,
                                                      int cols, float* __restrict__ sum,
                                                      float* __restrict__ sumsq) {
  __shared__ float ls[2048], ls2[2048];
  int tid = threadIdx.x;
  int stride = gridDim.x * 256;  // divisible by cols/8
  float s[8], s2[8];
#pragma unroll
  for (int k = 0; k < 8; ++k) { s[k] = 0.f; s2[k] = 0.f; }
  for (int i = blockIdx.x * 256 + tid; i < units; i += stride) {
    short8 v = reinterpret_cast<const short8*>(X)[i];
#pragma unroll
    for (int k = 0; k < 8; ++k) {
      float f = b2f((ushort)v[k]);
      s[k] += f;
      s2[k] += f * f;
    }
  }
#pragma unroll
  for (int k = 0; k < 8; ++k) { ls[tid * 8 + k] = s[k]; ls2[tid * 8 + k] = s2[k]; }
  __syncthreads();
  if (tid < cols) {
    int P = cols >> 3;
    float a = 0.f, a2 = 0.f;
    for (int t = (tid >> 3); t < 256; t += P) {
      a += ls[t * 8 + (tid & 7)];
      a2 += ls2[t * 8 + (tid & 7)];
    }
    atomicAdd(&sum[tid], a);
    atomicAdd(&sumsq[tid], a2);
  }
}

// ---------------- dual per-column sum/sumsq over TWO [NPTS x 256] bf16 matrices, one pass
__global__ __launch_bounds__(256) void k_colstats_dual(const ushort* __restrict__ XA,
                                                       const ushort* __restrict__ XB,
                                                       float* __restrict__ sumA,
                                                       float* __restrict__ sumsqA,
                                                       float* __restrict__ sumB,
                                                       float* __restrict__ sumsqB) {
  __shared__ float ls[2048], ls2[2048];
  const int units = NPTS * 32;  // short8 units per matrix (256 cols)
  int tid = threadIdx.x;
  int stride = gridDim.x * 256;  // 256*256 = 65536, divisible by 32
  float sa[8], s2a[8], sb[8], s2b[8];
#pragma unroll
  for (int k = 0; k < 8; ++k) { sa[k] = 0.f; s2a[k] = 0.f; sb[k] = 0.f; s2b[k] = 0.f; }
  for (int i = blockIdx.x * 256 + tid; i < units; i += stride) {
    short8 va = reinterpret_cast<const short8*>(XA)[i];
    short8 vb = reinterpret_cast<const short8*>(XB)[i];
#pragma unroll
    for (int k = 0; k < 8; ++k) {
      float fa = b2f((ushort)va[k]);
      sa[k] += fa; s2a[k] += fa * fa;
      float fb = b2f((ushort)vb[k]);
      sb[k] += fb; s2b[k] += fb * fb;
    }
  }
  // reduce set A
#pragma unroll
  for (int k = 0; k < 8; ++k) { ls[tid * 8 + k] = sa[k]; ls2[tid * 8 + k] = s2a[k]; }
  __syncthreads();
  {
    float a = 0.f, a2 = 0.f;
    for (int t = (tid >> 3); t < 256; t += 32) {
      a += ls[t * 8 + (tid & 7)];
      a2 += ls2[t * 8 + (tid & 7)];
    }
    atomicAdd(&sumA[tid], a);
    atomicAdd(&sumsqA[tid], a2);
  }
  __syncthreads();
  // reduce set B
#pragma unroll
  for (int k = 0; k < 8; ++k) { ls[tid * 8 + k] = sb[k]; ls2[tid * 8 + k] = s2b[k]; }
  __syncthreads();
  {
    float a = 0.f, a2 = 0.f;
    for (int t = (tid >> 3); t < 256; t += 32) {
      a += ls[t * 8 + (tid & 7)];
      a2 += ls2[t * 8 + (tid & 7)];
    }
    atomicAdd(&sumB[tid], a);
    atomicAdd(&sumsqB[tid], a2);
  }
}

// ---------------- bn + leaky on bf16 [N,64] -> bf16
__global__ __launch_bounds__(256) void k_normb(const ushort* __restrict__ X,
                                               const float* __restrict__ sum,
                                               const float* __restrict__ sumsq,
                                               const float* __restrict__ g,
                                               const float* __restrict__ b,
                                               ushort* __restrict__ out) {
  __shared__ float sc[64], sh[64];
  int tid = threadIdx.x;
  if (tid < 64) {
    float m = sum[tid] * (1.0f / NPTS);
    float v = sumsq[tid] * (1.0f / NPTS) - m * m;
    float s = g[tid] * rsqrtf(v + EPS);
    sc[tid] = s;
    sh[tid] = b[tid] - m * s;
  }
  __syncthreads();
  const int units = NPTS * 8;  // short8 units
  int stride = gridDim.x * 256;
  for (int i = blockIdx.x * 256 + tid; i < units; i += stride) {
    short8 v = reinterpret_cast<const short8*>(X)[i];
    int cb = (i & 7) * 8;
    short8 o;
#pragma unroll
    for (int k = 0; k < 8; ++k) {
      float a = b2f((ushort)v[k]) * sc[cb + k] + sh[cb + k];
      a = a > 0.f ? a : SLOPE * a;
      o[k] = (short)f2b(a);
    }
    reinterpret_cast<short8*>(out)[i] = o;
  }
}

// ---------------- fused KPConv: gather -> stage1 MFMA -> stage2 MFMA -> unary2 MFMA
// block = 256 threads (4 waves), 16 points. Verified round-4 core; delta this round:
// rxyz staged per point in LDS (s_r, bank-skewed h+(h>>3) index) — j-loop reads ONE
// ds_read_b128 broadcast instead of 3 ds_bpermutes (24 -> 9 DS ops/point for w-comp).
__global__ __launch_bounds__(256, 3) void k_kpfused(const ushort* __restrict__ X1b,
                                                    const float* __restrict__ xyz,
                                                    const int* __restrict__ nidx,
                                                    const float* __restrict__ kpp,
                                                    const ushort* __restrict__ kws,
                                                    const ushort* __restrict__ w2s,
                                                    ushort* __restrict__ Y3b) {
  __shared__ ushort s_xT[4][64][32];  // [wave][d][h ^ swz] gathered neighbor feats (transposed)
  __shared__ ushort s_fk[30 * 512];   // fk in stage-2 A-operand layout, 16 pts x 960
  __shared__ ushort s_y2[2 * 512];    // Y2 in u2 A-operand layout, 16 pts x 64
  __shared__ float4 s_r[4][36];       // [wave][h + (h>>3)] per-point rel coords (bank-skewed)
  int tid = threadIdx.x;
  int w = tid >> 6, lane = tid & 63;
  int q = lane >> 4, nn = lane & 15;
  int l8 = lane >> 3, c8 = lane & 7;
  int n_base = blockIdx.x * 16;

  int kidx = nn < 15 ? nn : 0;
  float kpx = kpp[kidx * 3 + 0], kpy = kpp[kidx * 3 + 1], kpz = kpp[kidx * 3 + 2];

  // ---- hoisted global loads: neighbor ids + relative coords for all 4 points
  int nb[4];
  float rx[4], ry[4], rz[4];
#pragma unroll
  for (int p = 0; p < 4; ++p) {
    int n = n_base + w * 4 + p;
    nb[p] = 0; rx[p] = 0.f; ry[p] = 0.f; rz[p] = 0.f;
    if (lane < 32) {
      int t = nidx[n * NBH + lane];
      nb[p] = t;
      rx[p] = xyz[t * 3 + 0] - xyz[n * 3 + 0];
      ry[p] = xyz[t * 3 + 1] - xyz[n * 3 + 1];
      rz[p] = xyz[t * 3 + 2] - xyz[n * 3 + 2];
    }
  }
  // ---- issue all 16 gather loads (4 points x 4 iters, 16B/lane) into registers
  short8 g[4][4];
#pragma unroll
  for (int p = 0; p < 4; ++p)
#pragma unroll
    for (int it = 0; it < 4; ++it) {
      int nbh = __shfl(nb[p], it * 8 + l8);
      g[p][it] = *reinterpret_cast<const short8*>(X1b + (size_t)nbh * 64 + c8 * 8);
    }

#pragma unroll
  for (int p = 0; p < 4; ++p) {
    // stage this point's rel coords in LDS (skewed index: banks disjoint per q-group)
    if (lane < 32) s_r[w][lane + (lane >> 3)] = make_float4(rx[p], ry[p], rz[p], 0.f);
    // A-frag: af[j] = w[h=q*8+j][kpt=nn] (bf16); coords via broadcast b128 LDS read
    short8 af;
#pragma unroll
    for (int j = 0; j < 8; ++j) {
      float4 rr = s_r[w][q * 8 + j + q];  // (h=q*8+j) + (h>>3)=q
      float dx = rr.x - kpx;
      float dy = rr.y - kpy;
      float dz = rr.z - kpz;
      float dist = sqrtf(dx * dx + dy * dy + dz * dz);
      float wv = fmaxf(1.0f - dist * (1.0f / INFL), 0.0f);
      if (nn == 15) wv = 0.f;
      af[j] = (short)f2b(wv);
    }
    // transpose gathered rows into s_xT with XOR swizzle (baseline-verified layout)
#pragma unroll
    for (int it = 0; it < 4; ++it) {
      int hh = it * 8 + l8;
      int hcol = hh ^ ((c8 & 3) << 3);  // key = (d>>3)&3 = c8&3
#pragma unroll
      for (int u = 0; u < 8; ++u) s_xT[w][c8 * 8 + u][hcol] = (ushort)g[p][it][u];
    }
    // stage-1 MFMA: fk[kpt][d] = sum_h w[h][kpt] * x[h][d]
    f32x4 acc[4];
#pragma unroll
    for (int c = 0; c < 4; ++c) {
      int d = c * 16 + nn;
      int key = (d >> 3) & 3;
      short8 bf = *reinterpret_cast<const short8*>(&s_xT[w][d][(q ^ key) << 3]);
      acc[c] = __builtin_amdgcn_mfma_f32_16x16x32_bf16(af, bf, (f32x4){0.f, 0.f, 0.f, 0.f}, 0, 0, 0);
    }
    // write fk -> s_fk in stage-2 A layout (kappa = kpt*64 + d), XOR-swizzled (conflict-free)
    int m = w * 4 + p;
#pragma unroll
    for (int c = 0; c < 4; ++c) {
#pragma unroll
      for (int r = 0; r < 4; ++r) {
        int kpt = q * 4 + r;
        if (kpt < 15) {
          int kap = kpt * 64 + c * 16 + nn;
          int ch = kap >> 5, t = kap & 31;
          int tp = t ^ (((ch >> 3) & 3) << 3);
          s_fk[ch * 512 + m * 32 + tp] = f2b(acc[c][r]);
        }
      }
    }
  }
  __syncthreads();

  // stage-2: Y2[16 x 64] = FK[16 x 960] * kw[960 x 64]; wave w owns col tile w
  f32x4 acc2 = (f32x4){0.f, 0.f, 0.f, 0.f};
  for (int ch = 0; ch < 30; ++ch) {
    int key = (ch >> 3) & 3;
    short8 a = *reinterpret_cast<const short8*>(&s_fk[ch * 512 + nn * 32 + ((q ^ key) << 3)]);
    short8 b = *reinterpret_cast<const short8*>(kws + (size_t)ch * 2048 + w * 512 + nn * 32 + q * 8);
    acc2 = __builtin_amdgcn_mfma_f32_16x16x32_bf16(a, b, acc2, 0, 0, 0);
  }
  {
    int e = w * 16 + nn;
    int ch2 = e >> 5, t = e & 31;
#pragma unroll
    for (int r = 0; r < 4; ++r) {
      int mm = q * 4 + r;
      int tp = t ^ (((mm >> 2) & 3) << 3);
      s_y2[ch2 * 512 + mm * 32 + tp] = f2b(acc2[r]);
    }
  }
  __syncthreads();

  // unary_2: Y3[16 x 256] = Y2[16 x 64] * W2[64 x 256]; wave w owns col tiles w*4..w*4+3
  short8 a0, a1;
  {
    int key = (nn >> 2) & 3;
    a0 = *reinterpret_cast<const short8*>(&s_y2[0 * 512 + nn * 32 + ((q ^ key) << 3)]);
    a1 = *reinterpret_cast<const short8*>(&s_y2[1 * 512 + nn * 32 + ((q ^ key) << 3)]);
  }
#pragma unroll
  for (int t4 = 0; t4 < 4; ++t4) {
    int ct = w * 4 + t4;
    short8 b0 = *reinterpret_cast<const short8*>(w2s + (0 * 16 + ct) * 512 + nn * 32 + q * 8);
    short8 b1 = *reinterpret_cast<const short8*>(w2s + (1 * 16 + ct) * 512 + nn * 32 + q * 8);
    f32x4 a = __builtin_amdgcn_mfma_f32_16x16x32_bf16(a0, b0, (f32x4){0.f, 0.f, 0.f, 0.f}, 0, 0, 0);
    a = __builtin_amdgcn_mfma_f32_16x16x32_bf16(a1, b1, a, 0, 0, 0);
#pragma unroll
    for (int r = 0; r < 4; ++r)
      Y3b[(size_t)(n_base + q * 4 + r) * 256 + ct * 16 + nn] = f2b(a[r]);
  }
}

// ---------------- final: out = leaky(bn(Y3b)) + bn(YSCb), f32 out
__global__ __launch_bounds__(256) void k_final(const ushort* __restrict__ Y3,
                                               const ushort* __restrict__ YSC,
                                               const float* __restrict__ s3,
                                               const float* __restrict__ ss3,
                                               const float* __restrict__ g2,
                                               const float* __restrict__ b2,
                                               const float* __restrict__ ssc,
                                               const float* __restrict__ sssc,
                                               const float* __restrict__ gsc,
                                               const float* __restrict__ bsc,
                                               float* __restrict__ out) {
  __shared__ float sc3[256], sh3[256], scc[256], shc[256];
  int tid = threadIdx.x;
  {
    float m = s3[tid] * (1.0f / NPTS);
    float v = ss3[tid] * (1.0f / NPTS) - m * m;
    float s = g2[tid] * rsqrtf(v + EPS);
    sc3[tid] = s;
    sh3[tid] = b2[tid] - m * s;
    m = ssc[tid] * (1.0f / NPTS);
    v = sssc[tid] * (1.0f / NPTS) - m * m;
    s = gsc[tid] * rsqrtf(v + EPS);
    scc[tid] = s;
    shc[tid] = bsc[tid] - m * s;
  }
  __syncthreads();
  const int units = NPTS * 32;  // short8 units per matrix
  int stride = gridDim.x * 256;
  for (int i = blockIdx.x * 256 + tid; i < units; i += stride) {
    short8 a = reinterpret_cast<const short8*>(Y3)[i];
    short8 b = reinterpret_cast<const short8*>(YSC)[i];
    int cb = (i & 31) * 8;
    float o[8];
#pragma unroll
    for (int k = 0; k < 8; ++k) {
      float x = b2f((ushort)a[k]) * sc3[cb + k] + sh3[cb + k];
      x = x > 0.f ? x : SLOPE * x;
      o[k] = x + b2f((ushort)b[k]) * scc[cb + k] + shc[cb + k];
    }
    float4* O4 = reinterpret_cast<float4*>(out + (size_t)i * 8);
    O4[0] = make_float4(o[0], o[1], o[2], o[3]);
    O4[1] = make_float4(o[4], o[5], o[6], o[7]);
  }
}

extern "C" void kernel_launch(void* const* d_in, const int* in_sizes, int n_in,
                              void* d_out, int out_size, void* d_ws, size_t ws_size,
                              hipStream_t stream) {
  const float* feats = (const float*)d_in[0];
  const float* xyz   = (const float*)d_in[1];
  const int* nidx    = (const int*)d_in[3];
  const float* W1    = (const float*)d_in[4];
  const float* g1    = (const float*)d_in[5];
  const float* b1    = (const float*)d_in[6];
  const float* kpp   = (const float*)d_in[7];
  const float* kw    = (const float*)d_in[8];
  const float* W2    = (const float*)d_in[9];
  const float* g2    = (const float*)d_in[10];
  const float* b2    = (const float*)d_in[11];
  const float* Wsc   = (const float*)d_in[12];
  const float* gsc   = (const float*)d_in[13];
  const float* bsc   = (const float*)d_in[14];
  float* out = (float*)d_out;

  // workspace (bytes): featsb 20.48M | X1r 10.24M | X1b 10.24M | Y3b 40.96M | YSCb 40.96M | weights | stats
  char* ws = (char*)d_ws;
  ushort* featsb = (ushort*)ws;
  ushort* X1r    = (ushort*)(ws + 20480000);
  ushort* X1b    = (ushort*)(ws + 30720000);
  ushort* Y3b    = (ushort*)(ws + 40960000);
  ushort* YSCb   = (ushort*)(ws + 81920000);
  ushort* w1s    = (ushort*)(ws + 122880000);
  ushort* w2s    = w1s + 8192;
  ushort* wscs   = w2s + 16384;
  ushort* kws    = wscs + 32768;
  float*  ST     = (float*)(kws + 61440);
  float *S1 = ST, *SS1 = ST + 64;
  float *S3 = ST + 128, *SS3 = ST + 384;
  float *SSC = ST + 640, *SSSC = ST + 896;

  hipMemsetAsync(ST, 0, 1152 * sizeof(float), stream);
  k_prep<<<2048, 256, 0, stream>>>(feats, W1, W2, Wsc, kw, featsb, w1s, w2s, wscs, kws);
  // unary_1
  k_gemm_mfma<64><<<1250, 256, 0, stream>>>(featsb, w1s, X1r, 128);
  k_colstats_b16<<<256, 256, 0, stream>>>(X1r, NPTS * 8, 64, S1, SS1);
  k_normb<<<512, 256, 0, stream>>>(X1r, S1, SS1, g1, b1, X1b);
  // shortcut (independent; stats deferred to the dual pass after kpfused)
  k_gemm_mfma<256><<<1250, 256, 0, stream>>>(featsb, wscs, YSCb, 128);
  // fused KPConv + unary_2
  k_kpfused<<<NPTS / 16, 256, 0, stream>>>(X1b, xyz, nidx, kpp, kws, w2s, Y3b);
  // one-pass column stats over Y3b and YSCb together
  k_colstats_dual<<<256, 256, 0, stream>>>(Y3b, YSCb, S3, SS3, SSC, SSSC);
  // out = leaky(bn(Y3b)) + bn(YSCb)
  k_final<<<1024, 256, 0, stream>>>(Y3b, YSCb, S3, SS3, g2, b2, SSC, SSSC, gsc, bsc, out);
}

// Round 10
// 345.908 us; speedup vs baseline: 1.7633x; 1.0469x over previous
//
#include <hip/hip_runtime.h>
#include <math.h>

#define NPTS 80000
#define NBH 32
#define KP 15
#define CIN 128
#define COUT 256
#define D2 64
#define INFL 0.4f
#define EPS 1e-5f
#define SLOPE 0.2f

typedef __attribute__((ext_vector_type(8))) short short8;
typedef __attribute__((ext_vector_type(4))) float f32x4;

__device__ inline ushort f2b(float x) {
  unsigned u = __float_as_uint(x);
  return (ushort)((u + 0x7FFFu + ((u >> 16) & 1u)) >> 16);  // RNE
}
__device__ inline float b2f(ushort v) { return __uint_as_float(((unsigned)v) << 16); }

// ---------------- prep: feats f32->bf16, weights f32->bf16 swizzled to MFMA B-operand order
// B fragment order: Bsw[chunk][ctile][nn][q][j] <- B[k][n], k=chunk*32+q*8+j, n=ctile*16+nn
__global__ __launch_bounds__(256) void k_prep(const float* __restrict__ feats,
                                              const float* __restrict__ W1,
                                              const float* __restrict__ W2,
                                              const float* __restrict__ Wsc,
                                              const float* __restrict__ kw,
                                              ushort* __restrict__ featsb,
                                              ushort* __restrict__ w1s,
                                              ushort* __restrict__ w2s,
                                              ushort* __restrict__ wscs,
                                              ushort* __restrict__ kws) {
  const int NF4 = NPTS * CIN / 4;
  const int TOT = NF4 + 118784;
  int stride = gridDim.x * 256;
  for (int i = blockIdx.x * 256 + threadIdx.x; i < TOT; i += stride) {
    if (i < NF4) {
      float4 v = reinterpret_cast<const float4*>(feats)[i];
      ushort4 o;
      o.x = f2b(v.x); o.y = f2b(v.y); o.z = f2b(v.z); o.w = f2b(v.w);
      reinterpret_cast<ushort4*>(featsb)[i] = o;
    } else {
      int j = i - NF4;
      const float* src;
      ushort* dst;
      int logN;
      if (j < 8192)       { src = W1;  dst = w1s;  logN = 6; }
      else if (j < 24576) { j -= 8192;  src = W2;  dst = w2s;  logN = 8; }
      else if (j < 57344) { j -= 24576; src = Wsc; dst = wscs; logN = 8; }
      else                { j -= 57344; src = kw;  dst = kws;  logN = 6; }
      int N = 1 << logN, NT = N >> 4;
      int k = j >> logN, n = j & (N - 1);
      int dsti = ((k >> 5) * NT + (n >> 4)) * 512 + (n & 15) * 32 + ((k >> 3) & 3) * 8 + (k & 7);
      dst[dsti] = f2b(src[j]);
    }
  }
}

// ---------------- register-resident MFMA GEMM body (K=128), bf16 out
template <int NT>
__device__ inline void gemm_body(const ushort* __restrict__ A, const ushort* __restrict__ Bsw,
                                 ushort* __restrict__ Cb, int bid) {
  constexpr int NCOLS = NT * 16;
  int tid = threadIdx.x;
  int wave = tid >> 6, lane = tid & 63;
  int nn = lane & 15, q = lane >> 4;
  int row0 = bid * 64 + wave * 16;
  f32x4 acc[NT];
#pragma unroll
  for (int c = 0; c < NT; ++c) acc[c] = (f32x4){0.f, 0.f, 0.f, 0.f};
  const ushort* ap = A + (size_t)(row0 + nn) * CIN + q * 8;
#pragma unroll
  for (int ch = 0; ch < 4; ++ch) {
    short8 af = *reinterpret_cast<const short8*>(ap + ch * 32);
    const ushort* bp = Bsw + (size_t)ch * NT * 512 + nn * 32 + q * 8;
#pragma unroll
    for (int c = 0; c < NT; ++c) {
      short8 bf = *reinterpret_cast<const short8*>(bp + c * 512);
      acc[c] = __builtin_amdgcn_mfma_f32_16x16x32_bf16(af, bf, acc[c], 0, 0, 0);
    }
  }
#pragma unroll
  for (int c = 0; c < NT; ++c)
#pragma unroll
    for (int r = 0; r < 4; ++r)
      Cb[(size_t)(row0 + q * 4 + r) * NCOLS + c * 16 + nn] = f2b(acc[c][r]);
}

// ---------------- both GEMMs in one dispatch, spatially partitioned by blockIdx
// (per-thread registers = max of the two bodies, NOT the sum — avoids round-6 spill)
__global__ __launch_bounds__(256) void k_gemm_both(const ushort* __restrict__ A,
                                                   const ushort* __restrict__ w1s,
                                                   const ushort* __restrict__ wscs,
                                                   ushort* __restrict__ X1r,
                                                   ushort* __restrict__ YSCb) {
  int bid = blockIdx.x;
  if (bid < 1250) gemm_body<4>(A, w1s, X1r, bid);
  else            gemm_body<16>(A, wscs, YSCb, bid - 1250);
}

// ---------------- per-column sum/sumsq over bf16 matrix (vectorized, LDS reduce)
__global__ __launch_bounds__(256) void k_colstats_b16(const ushort* __restrict__ X, int units,
                                                      int cols, float* __restrict__ sum,
                                                      float* __restrict__ sumsq) {
  __shared__ float ls[2048], ls2[2048];
  int tid = threadIdx.x;
  int stride = gridDim.x * 256;  // divisible by cols/8
  float s[8], s2[8];
#pragma unroll
  for (int k = 0; k < 8; ++k) { s[k] = 0.f; s2[k] = 0.f; }
  for (int i = blockIdx.x * 256 + tid; i < units; i += stride) {
    short8 v = reinterpret_cast<const short8*>(X)[i];
#pragma unroll
    for (int k = 0; k < 8; ++k) {
      float f = b2f((ushort)v[k]);
      s[k] += f;
      s2[k] += f * f;
    }
  }
#pragma unroll
  for (int k = 0; k < 8; ++k) { ls[tid * 8 + k] = s[k]; ls2[tid * 8 + k] = s2[k]; }
  __syncthreads();
  if (tid < cols) {
    int P = cols >> 3;
    float a = 0.f, a2 = 0.f;
    for (int t = (tid >> 3); t < 256; t += P) {
      a += ls[t * 8 + (tid & 7)];
      a2 += ls2[t * 8 + (tid & 7)];
    }
    atomicAdd(&sum[tid], a);
    atomicAdd(&sumsq[tid], a2);
  }
}

// ---------------- dual per-column sum/sumsq over TWO [NPTS x 256] bf16 matrices, one pass
__global__ __launch_bounds__(256) void k_colstats_dual(const ushort* __restrict__ XA,
                                                       const ushort* __restrict__ XB,
                                                       float* __restrict__ sumA,
                                                       float* __restrict__ sumsqA,
                                                       float* __restrict__ sumB,
                                                       float* __restrict__ sumsqB) {
  __shared__ float ls[2048], ls2[2048];
  const int units = NPTS * 32;  // short8 units per matrix (256 cols)
  int tid = threadIdx.x;
  int stride = gridDim.x * 256;  // 256*256 = 65536, divisible by 32
  float sa[8], s2a[8], sb[8], s2b[8];
#pragma unroll
  for (int k = 0; k < 8; ++k) { sa[k] = 0.f; s2a[k] = 0.f; sb[k] = 0.f; s2b[k] = 0.f; }
  for (int i = blockIdx.x * 256 + tid; i < units; i += stride) {
    short8 va = reinterpret_cast<const short8*>(XA)[i];
    short8 vb = reinterpret_cast<const short8*>(XB)[i];
#pragma unroll
    for (int k = 0; k < 8; ++k) {
      float fa = b2f((ushort)va[k]);
      sa[k] += fa; s2a[k] += fa * fa;
      float fb = b2f((ushort)vb[k]);
      sb[k] += fb; s2b[k] += fb * fb;
    }
  }
  // reduce set A
#pragma unroll
  for (int k = 0; k < 8; ++k) { ls[tid * 8 + k] = sa[k]; ls2[tid * 8 + k] = s2a[k]; }
  __syncthreads();
  {
    float a = 0.f, a2 = 0.f;
    for (int t = (tid >> 3); t < 256; t += 32) {
      a += ls[t * 8 + (tid & 7)];
      a2 += ls2[t * 8 + (tid & 7)];
    }
    atomicAdd(&sumA[tid], a);
    atomicAdd(&sumsqA[tid], a2);
  }
  __syncthreads();
  // reduce set B
#pragma unroll
  for (int k = 0; k < 8; ++k) { ls[tid * 8 + k] = sb[k]; ls2[tid * 8 + k] = s2b[k]; }
  __syncthreads();
  {
    float a = 0.f, a2 = 0.f;
    for (int t = (tid >> 3); t < 256; t += 32) {
      a += ls[t * 8 + (tid & 7)];
      a2 += ls2[t * 8 + (tid & 7)];
    }
    atomicAdd(&sumB[tid], a);
    atomicAdd(&sumsqB[tid], a2);
  }
}

// ---------------- bn + leaky on bf16 [N,64] -> bf16
__global__ __launch_bounds__(256) void k_normb(const ushort* __restrict__ X,
                                               const float* __restrict__ sum,
                                               const float* __restrict__ sumsq,
                                               const float* __restrict__ g,
                                               const float* __restrict__ b,
                                               ushort* __restrict__ out) {
  __shared__ float sc[64], sh[64];
  int tid = threadIdx.x;
  if (tid < 64) {
    float m = sum[tid] * (1.0f / NPTS);
    float v = sumsq[tid] * (1.0f / NPTS) - m * m;
    float s = g[tid] * rsqrtf(v + EPS);
    sc[tid] = s;
    sh[tid] = b[tid] - m * s;
  }
  __syncthreads();
  const int units = NPTS * 8;  // short8 units
  int stride = gridDim.x * 256;
  for (int i = blockIdx.x * 256 + tid; i < units; i += stride) {
    short8 v = reinterpret_cast<const short8*>(X)[i];
    int cb = (i & 7) * 8;
    short8 o;
#pragma unroll
    for (int k = 0; k < 8; ++k) {
      float a = b2f((ushort)v[k]) * sc[cb + k] + sh[cb + k];
      a = a > 0.f ? a : SLOPE * a;
      o[k] = (short)f2b(a);
    }
    reinterpret_cast<short8*>(out)[i] = o;
  }
}

// ---------------- fused KPConv: gather -> stage1 MFMA -> stage2 MFMA -> unary2 MFMA
// block = 256 threads (4 waves), 16 points. Verified round-9 core; deltas this round:
// (a) s_fk grown to 32 chunks -> fk write branchless, kpt=15 garbage lands in scratch
//     chunks 30/31 (stage-2 reads ch<30 only); (b) lane nn==15 uses a poisoned far
//     kernel-point (1e9) so wv computes to exactly 0 without per-j cndmask.
__global__ __launch_bounds__(256, 3) void k_kpfused(const ushort* __restrict__ X1b,
                                                    const float* __restrict__ xyz,
                                                    const int* __restrict__ nidx,
                                                    const float* __restrict__ kpp,
                                                    const ushort* __restrict__ kws,
                                                    const ushort* __restrict__ w2s,
                                                    ushort* __restrict__ Y3b) {
  __shared__ ushort s_xT[4][64][32];  // [wave][d][h ^ swz] gathered neighbor feats (transposed)
  __shared__ ushort s_fk[32 * 512];   // fk in stage-2 A layout; chunks 30/31 = scratch (kpt 15)
  __shared__ ushort s_y2[2 * 512];    // Y2 in u2 A-operand layout, 16 pts x 64
  __shared__ float4 s_r[4][36];       // [wave][h + (h>>3)] per-point rel coords (bank-skewed)
  int tid = threadIdx.x;
  int w = tid >> 6, lane = tid & 63;
  int q = lane >> 4, nn = lane & 15;
  int l8 = lane >> 3, c8 = lane & 7;
  int n_base = blockIdx.x * 16;

  int kidx = nn < 15 ? nn : 0;
  float kpx = kpp[kidx * 3 + 0], kpy = kpp[kidx * 3 + 1], kpz = kpp[kidx * 3 + 2];
  if (nn == 15) { kpx = 1.0e9f; kpy = 1.0e9f; kpz = 1.0e9f; }  // wv -> exactly 0 for kpt 15

  // ---- hoisted global loads: neighbor ids + relative coords for all 4 points
  int nb[4];
  float rx[4], ry[4], rz[4];
#pragma unroll
  for (int p = 0; p < 4; ++p) {
    int n = n_base + w * 4 + p;
    nb[p] = 0; rx[p] = 0.f; ry[p] = 0.f; rz[p] = 0.f;
    if (lane < 32) {
      int t = nidx[n * NBH + lane];
      nb[p] = t;
      rx[p] = xyz[t * 3 + 0] - xyz[n * 3 + 0];
      ry[p] = xyz[t * 3 + 1] - xyz[n * 3 + 1];
      rz[p] = xyz[t * 3 + 2] - xyz[n * 3 + 2];
    }
  }
  // ---- issue all 16 gather loads (4 points x 4 iters, 16B/lane) into registers
  short8 g[4][4];
#pragma unroll
  for (int p = 0; p < 4; ++p)
#pragma unroll
    for (int it = 0; it < 4; ++it) {
      int nbh = __shfl(nb[p], it * 8 + l8);
      g[p][it] = *reinterpret_cast<const short8*>(X1b + (size_t)nbh * 64 + c8 * 8);
    }

#pragma unroll
  for (int p = 0; p < 4; ++p) {
    // stage this point's rel coords in LDS (skewed index: banks disjoint per q-group)
    if (lane < 32) s_r[w][lane + (lane >> 3)] = make_float4(rx[p], ry[p], rz[p], 0.f);
    // A-frag: af[j] = w[h=q*8+j][kpt=nn] (bf16); coords via broadcast b128 LDS read
    short8 af;
#pragma unroll
    for (int j = 0; j < 8; ++j) {
      float4 rr = s_r[w][q * 8 + j + q];  // (h=q*8+j) + (h>>3)=q
      float dx = rr.x - kpx;
      float dy = rr.y - kpy;
      float dz = rr.z - kpz;
      float dist = sqrtf(dx * dx + dy * dy + dz * dz);
      float wv = fmaxf(1.0f - dist * (1.0f / INFL), 0.0f);
      af[j] = (short)f2b(wv);
    }
    // transpose gathered rows into s_xT with XOR swizzle (baseline-verified layout)
#pragma unroll
    for (int it = 0; it < 4; ++it) {
      int hh = it * 8 + l8;
      int hcol = hh ^ ((c8 & 3) << 3);  // key = (d>>3)&3 = c8&3
#pragma unroll
      for (int u = 0; u < 8; ++u) s_xT[w][c8 * 8 + u][hcol] = (ushort)g[p][it][u];
    }
    // stage-1 MFMA: fk[kpt][d] = sum_h w[h][kpt] * x[h][d]
    f32x4 acc[4];
#pragma unroll
    for (int c = 0; c < 4; ++c) {
      int d = c * 16 + nn;
      int key = (d >> 3) & 3;
      short8 bf = *reinterpret_cast<const short8*>(&s_xT[w][d][(q ^ key) << 3]);
      acc[c] = __builtin_amdgcn_mfma_f32_16x16x32_bf16(af, bf, (f32x4){0.f, 0.f, 0.f, 0.f}, 0, 0, 0);
    }
    // write fk -> s_fk in stage-2 A layout (kappa = kpt*64 + d), XOR-swizzled, branchless
    int m = w * 4 + p;
#pragma unroll
    for (int c = 0; c < 4; ++c) {
#pragma unroll
      for (int r = 0; r < 4; ++r) {
        int kpt = q * 4 + r;
        int kap = kpt * 64 + c * 16 + nn;
        int ch = kap >> 5, t = kap & 31;
        int tp = t ^ (((ch >> 3) & 3) << 3);
        s_fk[ch * 512 + m * 32 + tp] = f2b(acc[c][r]);
      }
    }
  }
  __syncthreads();

  // stage-2: Y2[16 x 64] = FK[16 x 960] * kw[960 x 64]; wave w owns col tile w
  f32x4 acc2 = (f32x4){0.f, 0.f, 0.f, 0.f};
  for (int ch = 0; ch < 30; ++ch) {
    int key = (ch >> 3) & 3;
    short8 a = *reinterpret_cast<const short8*>(&s_fk[ch * 512 + nn * 32 + ((q ^ key) << 3)]);
    short8 b = *reinterpret_cast<const short8*>(kws + (size_t)ch * 2048 + w * 512 + nn * 32 + q * 8);
    acc2 = __builtin_amdgcn_mfma_f32_16x16x32_bf16(a, b, acc2, 0, 0, 0);
  }
  {
    int e = w * 16 + nn;
    int ch2 = e >> 5, t = e & 31;
#pragma unroll
    for (int r = 0; r < 4; ++r) {
      int mm = q * 4 + r;
      int tp = t ^ (((mm >> 2) & 3) << 3);
      s_y2[ch2 * 512 + mm * 32 + tp] = f2b(acc2[r]);
    }
  }
  __syncthreads();

  // unary_2: Y3[16 x 256] = Y2[16 x 64] * W2[64 x 256]; wave w owns col tiles w*4..w*4+3
  short8 a0, a1;
  {
    int key = (nn >> 2) & 3;
    a0 = *reinterpret_cast<const short8*>(&s_y2[0 * 512 + nn * 32 + ((q ^ key) << 3)]);
    a1 = *reinterpret_cast<const short8*>(&s_y2[1 * 512 + nn * 32 + ((q ^ key) << 3)]);
  }
#pragma unroll
  for (int t4 = 0; t4 < 4; ++t4) {
    int ct = w * 4 + t4;
    short8 b0 = *reinterpret_cast<const short8*>(w2s + (0 * 16 + ct) * 512 + nn * 32 + q * 8);
    short8 b1 = *reinterpret_cast<const short8*>(w2s + (1 * 16 + ct) * 512 + nn * 32 + q * 8);
    f32x4 a = __builtin_amdgcn_mfma_f32_16x16x32_bf16(a0, b0, (f32x4){0.f, 0.f, 0.f, 0.f}, 0, 0, 0);
    a = __builtin_amdgcn_mfma_f32_16x16x32_bf16(a1, b1, a, 0, 0, 0);
#pragma unroll
    for (int r = 0; r < 4; ++r)
      Y3b[(size_t)(n_base + q * 4 + r) * 256 + ct * 16 + nn] = f2b(a[r]);
  }
}

// ---------------- final: out = leaky(bn(Y3b)) + bn(YSCb), f32 out
__global__ __launch_bounds__(256) void k_final(const ushort* __restrict__ Y3,
                                               const ushort* __restrict__ YSC,
                                               const float* __restrict__ s3,
                                               const float* __restrict__ ss3,
                                               const float* __restrict__ g2,
                                               const float* __restrict__ b2,
                                               const float* __restrict__ ssc,
                                               const float* __restrict__ sssc,
                                               const float* __restrict__ gsc,
                                               const float* __restrict__ bsc,
                                               float* __restrict__ out) {
  __shared__ float sc3[256], sh3[256], scc[256], shc[256];
  int tid = threadIdx.x;
  {
    float m = s3[tid] * (1.0f / NPTS);
    float v = ss3[tid] * (1.0f / NPTS) - m * m;
    float s = g2[tid] * rsqrtf(v + EPS);
    sc3[tid] = s;
    sh3[tid] = b2[tid] - m * s;
    m = ssc[tid] * (1.0f / NPTS);
    v = sssc[tid] * (1.0f / NPTS) - m * m;
    s = gsc[tid] * rsqrtf(v + EPS);
    scc[tid] = s;
    shc[tid] = bsc[tid] - m * s;
  }
  __syncthreads();
  const int units = NPTS * 32;  // short8 units per matrix
  int stride = gridDim.x * 256;
  for (int i = blockIdx.x * 256 + tid; i < units; i += stride) {
    short8 a = reinterpret_cast<const short8*>(Y3)[i];
    short8 b = reinterpret_cast<const short8*>(YSC)[i];
    int cb = (i & 31) * 8;
    float o[8];
#pragma unroll
    for (int k = 0; k < 8; ++k) {
      float x = b2f((ushort)a[k]) * sc3[cb + k] + sh3[cb + k];
      x = x > 0.f ? x : SLOPE * x;
      o[k] = x + b2f((ushort)b[k]) * scc[cb + k] + shc[cb + k];
    }
    float4* O4 = reinterpret_cast<float4*>(out + (size_t)i * 8);
    O4[0] = make_float4(o[0], o[1], o[2], o[3]);
    O4[1] = make_float4(o[4], o[5], o[6], o[7]);
  }
}

extern "C" void kernel_launch(void* const* d_in, const int* in_sizes, int n_in,
                              void* d_out, int out_size, void* d_ws, size_t ws_size,
                              hipStream_t stream) {
  const float* feats = (const float*)d_in[0];
  const float* xyz   = (const float*)d_in[1];
  const int* nidx    = (const int*)d_in[3];
  const float* W1    = (const float*)d_in[4];
  const float* g1    = (const float*)d_in[5];
  const float* b1    = (const float*)d_in[6];
  const float* kpp   = (const float*)d_in[7];
  const float* kw    = (const float*)d_in[8];
  const float* W2    = (const float*)d_in[9];
  const float* g2    = (const float*)d_in[10];
  const float* b2    = (const float*)d_in[11];
  const float* Wsc   = (const float*)d_in[12];
  const float* gsc   = (const float*)d_in[13];
  const float* bsc   = (const float*)d_in[14];
  float* out = (float*)d_out;

  // workspace (bytes): featsb 20.48M | X1r 10.24M | X1b 10.24M | Y3b 40.96M | YSCb 40.96M | weights | stats
  char* ws = (char*)d_ws;
  ushort* featsb = (ushort*)ws;
  ushort* X1r    = (ushort*)(ws + 20480000);
  ushort* X1b    = (ushort*)(ws + 30720000);
  ushort* Y3b    = (ushort*)(ws + 40960000);
  ushort* YSCb   = (ushort*)(ws + 81920000);
  ushort* w1s    = (ushort*)(ws + 122880000);
  ushort* w2s    = w1s + 8192;
  ushort* wscs   = w2s + 16384;
  ushort* kws    = wscs + 32768;
  float*  ST     = (float*)(kws + 61440);
  float *S1 = ST, *SS1 = ST + 64;
  float *S3 = ST + 128, *SS3 = ST + 384;
  float *SSC = ST + 640, *SSSC = ST + 896;

  hipMemsetAsync(ST, 0, 1152 * sizeof(float), stream);
  k_prep<<<2048, 256, 0, stream>>>(feats, W1, W2, Wsc, kw, featsb, w1s, w2s, wscs, kws);
  // both GEMMs co-scheduled in one dispatch (spatial block split)
  k_gemm_both<<<2500, 256, 0, stream>>>(featsb, w1s, wscs, X1r, YSCb);
  k_colstats_b16<<<256, 256, 0, stream>>>(X1r, NPTS * 8, 64, S1, SS1);
  k_normb<<<512, 256, 0, stream>>>(X1r, S1, SS1, g1, b1, X1b);
  // fused KPConv + unary_2
  k_kpfused<<<NPTS / 16, 256, 0, stream>>>(X1b, xyz, nidx, kpp, kws, w2s, Y3b);
  // one-pass column stats over Y3b and YSCb together
  k_colstats_dual<<<256, 256, 0, stream>>>(Y3b, YSCb, S3, SS3, SSC, SSSC);
  // out = leaky(bn(Y3b)) + bn(YSCb)
  k_final<<<1024, 256, 0, stream>>>(Y3b, YSCb, S3, SS3, g2, b2, SSC, SSSC, gsc, bsc, out);
}